// Round 5
// baseline (297.576 us; speedup 1.0000x reference)
//
#include <hip/hip_runtime.h>
#include <cmath>

// Sampler: B=256 rows, V=128000 vocab.
// out[0..255]         = tokens (as float values)
// out[256..256+B*V)   = final probs (min-p renormalized), mostly zeros
//
// K0: zero per-row candidate counters (in d_ws).
// K1: fill-kernel-shaped stream (4000 blocks x 256 thr, TLP-driven):
//     8 unguarded float4 loads + 8 zero stores per thread, gather candidates
//     (l >= 6.0, ~173/row expected, CAP=512 is 22 sigma) to global lists.
//     Grid stride == exactly 32 rows -> no div in loop, waves never straddle rows.
// K2: one block/row: candidates -> LDS, wave-0 register top-64 extraction +
//     exact top-k/top-p/min-p/inverse-CDF math. Bisection rescan fallback if
//     count outside [64,CAP] (never triggers on bench data).
//
// Exactness: softmax Z cancels in every renorm. Elements below the gather
// threshold cannot be in the top-64 (count>=64 candidates all exceed them),
// so reference top-k zeroes them -> candidate-only math is exact.
// Max candidate == row max (max always exceeds threshold when count>=1).

constexpr int BB  = 256;
constexpr int VV  = 128000;
constexpr int CAP = 512;
constexpr int IPL = CAP / 64;            // 8 items/lane in extraction
constexpr int NV4_ROW = VV / 4;          // 32000 float4 per row
constexpr int K1_THREADS = 256;
constexpr int K1_BLOCKS  = 4000;         // 1,024,000 threads total
constexpr int K1_STRIDE  = K1_THREADS * K1_BLOCKS;   // 1,024,000 float4
constexpr int K1_ROWSTRIDE = K1_STRIDE / NV4_ROW;    // exactly 32 rows
constexpr int K1_UNR = 8;                // 8 * 1,024,000 = 8,192,000 = B*V/4 exact
constexpr float T0 = 6.0f;

__global__ void k_zero(int* __restrict__ gcnt) { gcnt[threadIdx.x] = 0; }

__global__ __launch_bounds__(K1_THREADS) void k_stream(
    const float* __restrict__ logits, float* __restrict__ out,
    int* __restrict__ gcnt, float* __restrict__ gcl, int* __restrict__ gix) {
  const int idx  = blockIdx.x * K1_THREADS + threadIdx.x;   // [0, 1,024,000)
  const int row0 = idx / NV4_ROW;                           // magic-mul, once
  const int col  = (idx - row0 * NV4_ROW) << 2;             // loop-invariant
  const float4* in4 = reinterpret_cast<const float4*>(logits);
  float4* o4 = reinterpret_cast<float4*>(out + BB);

  float4 v[K1_UNR];
#pragma unroll
  for (int u = 0; u < K1_UNR; ++u) v[u] = in4[idx + u * K1_STRIDE];  // batched: 8 in flight
  const float4 z = make_float4(0.f, 0.f, 0.f, 0.f);
#pragma unroll
  for (int u = 0; u < K1_UNR; ++u) o4[idx + u * K1_STRIDE] = z;      // load-independent
#pragma unroll
  for (int u = 0; u < K1_UNR; ++u) {
    const float4 vv = v[u];
    if (vv.x >= T0 || vv.y >= T0 || vv.z >= T0 || vv.w >= T0) {      // ~rare
      const int row = row0 + u * K1_ROWSTRIDE;
      if (vv.x >= T0) { int p = atomicAdd(&gcnt[row], 1); if (p < CAP) { gcl[row*CAP+p] = vv.x; gix[row*CAP+p] = col;     } }
      if (vv.y >= T0) { int p = atomicAdd(&gcnt[row], 1); if (p < CAP) { gcl[row*CAP+p] = vv.y; gix[row*CAP+p] = col + 1; } }
      if (vv.z >= T0) { int p = atomicAdd(&gcnt[row], 1); if (p < CAP) { gcl[row*CAP+p] = vv.z; gix[row*CAP+p] = col + 2; } }
      if (vv.w >= T0) { int p = atomicAdd(&gcnt[row], 1); if (p < CAP) { gcl[row*CAP+p] = vv.w; gix[row*CAP+p] = col + 3; } }
    }
  }
}

__global__ __launch_bounds__(256) void k_select(
    const float* __restrict__ logits, const float* __restrict__ temps,
    const int* __restrict__ topks, const float* __restrict__ topps,
    const float* __restrict__ minps, const float* __restrict__ noise,
    const int* __restrict__ gcnt, const float* __restrict__ gcl,
    const int* __restrict__ gix, float* __restrict__ out) {
  const int row = blockIdx.x;
  const int tid = threadIdx.x;
  float* orow = out + BB + (size_t)row * VV;

  __shared__ float cl[CAP];
  __shared__ int   ci[CAP];
  __shared__ int   s_cnt;
  __shared__ float s_t, s_lo, s_hi;

  int cnt = gcnt[row];
  const int n0 = min(cnt, CAP);
  for (int i = tid; i < n0; i += 256) { cl[i] = gcl[row*CAP+i]; ci[i] = gix[row*CAP+i]; }
  __syncthreads();

  // ---- fallback bisection rescan (never triggers on bench data) ----
  if (cnt < 64 || cnt > CAP) {
    const float4* lp4 = reinterpret_cast<const float4*>(logits + (size_t)row * VV);
    if (tid == 0) { s_lo = (cnt > CAP) ? T0 : -1e30f; s_hi = (cnt > CAP) ? 1e30f : T0; }
    __syncthreads();
    for (int it = 0; it < 48 && (cnt < 64 || cnt > CAP); ++it) {
      if (tid == 0) {
        const float lo = s_lo, hi = s_hi;
        s_t = (lo <= -1e29f) ? hi - 8.0f : (hi >= 1e29f ? lo + 8.0f : 0.5f * (lo + hi));
        s_cnt = 0;
      }
      __syncthreads();
      const float t = s_t;
      for (int j = tid; j < NV4_ROW; j += 256) {
        const float4 v = lp4[j]; const int base = j << 2;
        if (v.x >= t) { int p = atomicAdd(&s_cnt, 1); if (p < CAP) { cl[p] = v.x; ci[p] = base;     } }
        if (v.y >= t) { int p = atomicAdd(&s_cnt, 1); if (p < CAP) { cl[p] = v.y; ci[p] = base + 1; } }
        if (v.z >= t) { int p = atomicAdd(&s_cnt, 1); if (p < CAP) { cl[p] = v.z; ci[p] = base + 2; } }
        if (v.w >= t) { int p = atomicAdd(&s_cnt, 1); if (p < CAP) { cl[p] = v.w; ci[p] = base + 3; } }
      }
      __syncthreads();
      cnt = s_cnt;
      if (tid == 0) { if (cnt > CAP) s_lo = s_t; else if (cnt < 64) s_hi = s_t; }
      __syncthreads();
    }
  }
  const int n = min(cnt, CAP);

  // ---- wave 0: register top-64 extraction + exact selection math ----
  if (tid < 64) {
    const int lane = tid;
    float rv[IPL]; int rix[IPL];
#pragma unroll
    for (int q = 0; q < IPL; ++q) {
      const int idx = lane + (q << 6);
      const bool ok = idx < n;
      rv[q]  = ok ? cl[idx] : -INFINITY;
      rix[q] = ok ? ci[idx] : 0x7fffffff;
    }
    const int n64 = min(n, 64);
    float lv = 0.0f; int iv = 0x7fffffff;
    for (int r = 0; r < n64; ++r) {          // uniform trip count
      float bv = rv[0]; int bi = rix[0];
#pragma unroll
      for (int q = 1; q < IPL; ++q) if (rv[q] > bv) { bv = rv[q]; bi = rix[q]; }
      for (int o = 32; o > 0; o >>= 1) {
        const float ov = __shfl_xor(bv, o, 64);
        const int   oi = __shfl_xor(bi, o, 64);
        if (ov > bv || (ov == bv && oi < bi)) { bv = ov; bi = oi; }
      }
#pragma unroll
      for (int q = 0; q < IPL; ++q) if (rix[q] == bi) { rv[q] = -INFINITY; rix[q] = 0x7fffffff; }
      if (lane == r) { lv = bv; iv = bi; }   // lane r owns r-th largest
    }

    const float Tv = temps[row];
    const float Mx = __shfl(lv, 0, 64) / Tv; // lane0 lv == row max; /T>0 monotone
    const bool valid = lane < n64;
    const float p = valid ? expf(lv / Tv - Mx) : 0.0f;   // Z cancels everywhere

    int k = topks[row];
    k = max(1, min(k, n64));
    const float kth = __shfl(p, k - 1, 64);
    const bool keepA = valid && (p >= kth);              // top-k (with ties)
    float S1 = keepA ? p : 0.0f;
    for (int o = 32; o > 0; o >>= 1) S1 += __shfl_xor(S1, o, 64);
    const float q = keepA ? (p / S1) : 0.0f;

    // top-p: keep while exclusive-cumsum < top_p; then q >= (min kept q)
    float cs = q;
    for (int o = 1; o < 64; o <<= 1) { const float v = __shfl_up(cs, o, 64); if (lane >= o) cs += v; }
    const float lhs = cs - q;                            // mimics (csum - sorted)
    const bool keepBp = keepA && (lhs < topps[row]);
    float thr = keepBp ? q : INFINITY;
    for (int o = 32; o > 0; o >>= 1) thr = fminf(thr, __shfl_xor(thr, o, 64));
    const bool keepB = keepA && (q >= thr);
    float S2 = keepB ? q : 0.0f;
    for (int o = 32; o > 0; o >>= 1) S2 += __shfl_xor(S2, o, 64);
    const float r2 = keepB ? (q / S2) : 0.0f;

    // min-p
    const float r0 = __shfl(r2, 0, 64);                  // lane 0 = max prob
    const bool keepC = keepB && (r2 >= minps[row] * r0);
    float S3 = keepC ? r2 : 0.0f;
    for (int o = 32; o > 0; o >>= 1) S3 += __shfl_xor(S3, o, 64);
    const float f = keepC ? (r2 / S3) : 0.0f;            // final probs

    // inverse-CDF sample in token-index order (zeros are fp no-ops)
    float cum = 0.0f, tot = 0.0f;
    for (int i2 = 0; i2 < 64; ++i2) {
      const float fi = __shfl(f, i2, 64);
      const int   ii = __shfl(iv, i2, 64);
      tot += fi;
      if (ii <= iv) cum += fi;             // same add sequence as tot at max-idx lane
    }
    const float target = noise[row] * tot;
    int tok = 0;                            // target<=0 -> argmax(cdf>=0) = 0
    if (target > 0.0f) {
      int cand = (keepC && cum >= target) ? iv : 0x7fffffff;
      for (int o = 32; o > 0; o >>= 1) cand = min(cand, __shfl_xor(cand, o, 64));
      if (cand == 0x7fffffff) {            // fp safety net
        int mi = keepC ? iv : -1;
        for (int o = 32; o > 0; o >>= 1) mi = max(mi, __shfl_xor(mi, o, 64));
        cand = (mi < 0) ? 0 : mi;
      }
      tok = cand;
    }

    if (keepC) orow[iv] = f;               // zero-writes from K1 already ordered
    if (lane == 0) out[row] = (float)tok;
  }
}

extern "C" void kernel_launch(void* const* d_in, const int* in_sizes, int n_in,
                              void* d_out, int out_size, void* d_ws, size_t ws_size,
                              hipStream_t stream) {
  const float* logits = (const float*)d_in[0];
  const float* temps  = (const float*)d_in[1];
  const int*   topks  = (const int*)d_in[2];
  const float* topps  = (const float*)d_in[3];
  const float* minps  = (const float*)d_in[4];
  const float* noise  = (const float*)d_in[5];
  float* out = (float*)d_out;

  // ws layout: [256 x int counters][256*CAP floats][256*CAP ints]  (~1.05 MB)
  int*   gcnt = (int*)d_ws;
  float* gcl  = (float*)((char*)d_ws + 256 * sizeof(int));
  int*   gix  = (int*)((char*)d_ws + 256 * sizeof(int) + (size_t)BB * CAP * sizeof(float));

  k_zero<<<1, 256, 0, stream>>>(gcnt);
  k_stream<<<K1_BLOCKS, K1_THREADS, 0, stream>>>(logits, out, gcnt, gcl, gix);
  k_select<<<BB, 256, 0, stream>>>(logits, temps, topks, topps, minps, noise,
                                   gcnt, gcl, gix, out);
}